// Round 2
// baseline (543.867 us; speedup 1.0000x reference)
//
#include <hip/hip_runtime.h>
#include <math.h>

#define NN 10000
#define NE 160000

// ---------------- CSR build ----------------

__global__ __launch_bounds__(256) void deg_kernel(const int* __restrict__ src,
                                                  const int* __restrict__ dst,
                                                  int* __restrict__ deg,
                                                  int* __restrict__ cnt, int E) {
  int e = blockIdx.x * 256 + threadIdx.x;
  if (e < E) {
    atomicAdd(&deg[src[e]], 1);
    atomicAdd(&cnt[dst[e]], 1);
  }
}

// fused: dinv (from deg-by-src) + exclusive scan of cnt (by dst) -> off
__global__ __launch_bounds__(1024) void scan_dinv_kernel(const int* __restrict__ cnt,
                                                         int* __restrict__ off,
                                                         const int* __restrict__ deg,
                                                         float* __restrict__ dinv, int n) {
  __shared__ int sh[1024];
  int t = threadIdx.x;
  for (int i = t; i < n; i += 1024) {
    int d = deg[i];
    dinv[i] = d > 0 ? 1.0f / sqrtf((float)d) : 0.0f;
  }
  int per = (n + 1023) / 1024;
  int base = t * per;
  int sum = 0;
  for (int i = 0; i < per; i++) {
    int idx = base + i;
    if (idx < n) sum += cnt[idx];
  }
  sh[t] = sum;
  __syncthreads();
  for (int d = 1; d < 1024; d <<= 1) {
    int v = (t >= d) ? sh[t - d] : 0;
    __syncthreads();
    if (t >= d) sh[t] += v;
    __syncthreads();
  }
  int run = (t > 0) ? sh[t - 1] : 0;
  for (int i = 0; i < per; i++) {
    int idx = base + i;
    if (idx < n) { off[idx] = run; run += cnt[idx]; }
  }
  if (t == 0) off[n] = sh[1023];
}

__global__ __launch_bounds__(256) void fill_kernel(const int* __restrict__ src,
                                                   const int* __restrict__ dst,
                                                   const float* __restrict__ dinv,
                                                   const int* __restrict__ off,
                                                   int* __restrict__ pos,
                                                   int* __restrict__ csrc,
                                                   float* __restrict__ cw, int E) {
  int e = blockIdx.x * 256 + threadIdx.x;
  if (e < E) {
    int s = src[e], d = dst[e];
    int slot = off[d] + atomicAdd(&pos[d], 1);
    csrc[slot] = s;
    cw[slot] = -dinv[s] * dinv[d];
  }
}

// ---------------- weight concat for push-through layers ----------------
// Wc [Fin][3*Fp]: cols [0,Fp)=W0-W2, [Fp,2Fp)=W1, [2Fp,3Fp)=W2 ; pad cols (f>=F) zeroed

__global__ __launch_bounds__(256) void wcat_kernel(const float* __restrict__ W,
                                                   float* __restrict__ Wc,
                                                   int Fin, int F, int Fp) {
  int i = blockIdx.x * 256 + threadIdx.x;
  int w3 = 3 * Fp;
  int total = Fin * w3;
  if (i >= total) return;
  int row = i / w3;
  int c = i - row * w3;
  int sec = c / Fp;
  int f = c - sec * Fp;
  float v = 0.0f;
  if (f < F) {
    if (sec == 0)      v = W[row * F + f] - W[2 * Fin * F + row * F + f];
    else if (sec == 1) v = W[Fin * F + row * F + f];
    else               v = W[2 * Fin * F + row * F + f];
  }
  Wc[i] = v;
}

// ---------------- GEMM: thread-per-row, W via uniform (scalar) loads ----------------
// Each thread owns one row of X and TN output cols in registers. W accesses are
// block-uniform -> s_load (SGPR broadcast into v_fma). No LDS in the hot loop.
// grid: (ceil(M/256), Nd/TN col-blocks, K-splits). use_atomic=1 -> atomicAdd into
// pre-zeroed Y (no bias/relu on that path).

template <int TN, bool AL4>
__global__ __launch_bounds__(256) void gemm_rs_kernel(
    const float* __restrict__ X, int ldx,
    const float* __restrict__ W, int ldw,
    const float* __restrict__ bias,
    float* __restrict__ Y, int ldy,
    int M, int kchunk, int Kd, int Nd, int relu, int use_atomic) {
  int r = blockIdx.x * 256 + threadIdx.x;
  if (r >= M) return;
  int col0 = blockIdx.y * TN;
  int k0 = blockIdx.z * kchunk;
  int kend = k0 + kchunk;
  if (kend > Kd) kend = Kd;

  float acc[TN];
#pragma unroll
  for (int c = 0; c < TN; c++) acc[c] = 0.f;
  const float* xrow = X + (size_t)r * ldx;

  for (; k0 + 4 <= kend; k0 += 4) {
    float xq[4];
    if (AL4) {
      float4 xv = *(const float4*)(xrow + k0);
      xq[0] = xv.x; xq[1] = xv.y; xq[2] = xv.z; xq[3] = xv.w;
    } else {
      xq[0] = xrow[k0]; xq[1] = xrow[k0 + 1]; xq[2] = xrow[k0 + 2]; xq[3] = xrow[k0 + 3];
    }
#pragma unroll
    for (int j = 0; j < 4; j++) {
      const float* wr = W + (size_t)(k0 + j) * ldw + col0;
#pragma unroll
      for (int c = 0; c < TN; c += 4) {
        float4 wv = *(const float4*)(wr + c);
        acc[c + 0] += xq[j] * wv.x;
        acc[c + 1] += xq[j] * wv.y;
        acc[c + 2] += xq[j] * wv.z;
        acc[c + 3] += xq[j] * wv.w;
      }
    }
  }
  for (; k0 < kend; k0++) {  // K tail (L1: 782 % 4 == 2)
    float xv = xrow[k0];
    const float* wr = W + (size_t)k0 * ldw + col0;
#pragma unroll
    for (int c = 0; c < TN; c += 4) {
      float4 wv = *(const float4*)(wr + c);
      acc[c + 0] += xv * wv.x;
      acc[c + 1] += xv * wv.y;
      acc[c + 2] += xv * wv.z;
      acc[c + 3] += xv * wv.w;
    }
  }

  float* yrow = Y + (size_t)r * ldy + col0;
  if (use_atomic) {
#pragma unroll
    for (int c = 0; c < TN; c++)
      if (col0 + c < Nd) atomicAdd(&yrow[c], acc[c]);
  } else {
#pragma unroll
    for (int c = 0; c < TN; c++) {
      int gc = col0 + c;
      if (gc < Nd) {
        float v = acc[c] + (bias ? bias[gc] : 0.f);
        if (relu) v = fmaxf(v, 0.f);
        yrow[c] = v;
      }
    }
  }
}

// ---------------- SpMM: wave-per-node ----------------
// lane = edge_slot * C + chunk (C = 2^C_log2 float4-chunks of features).
// Each lane gathers one edge's float4; butterfly-reduce over edge_slot bits.
// Y[node] = alpha * (L_hat X)[node] + beta * add[node] (+bias)(+relu), cols < Fstore.

__global__ __launch_bounds__(256) void spmm_kernel(
    const int* __restrict__ off,
    const int* __restrict__ csrc,
    const float* __restrict__ cw,
    const float* __restrict__ X, int ldx,
    float* __restrict__ Y, int ldy,
    const float* __restrict__ add, int lda,
    const float* __restrict__ bias,
    float alpha, float beta,
    int n, int C_log2, int Fstore, int relu) {
  int wave_in_blk = threadIdx.x >> 6;
  int lane = threadIdx.x & 63;
  int node = blockIdx.x * 4 + wave_in_blk;
  if (node >= n) return;
  int C = 1 << C_log2;
  int chunk = lane & (C - 1);
  int eslot = lane >> C_log2;
  int Epar = 64 >> C_log2;

  int j0 = off[node], j1 = off[node + 1];
  float sx = 0.f, sy = 0.f, sz = 0.f, sw = 0.f;
  for (int j = j0 + eslot; j < j1; j += Epar) {
    int sn = csrc[j];
    float w = cw[j];
    float4 xv = *(const float4*)(X + (size_t)sn * ldx + (chunk << 2));
    sx += w * xv.x; sy += w * xv.y; sz += w * xv.z; sw += w * xv.w;
  }
  for (int st = C; st < 64; st <<= 1) {
    sx += __shfl_xor(sx, st);
    sy += __shfl_xor(sy, st);
    sz += __shfl_xor(sz, st);
    sw += __shfl_xor(sw, st);
  }
  if (eslot == 0) {
    float vv[4] = {sx, sy, sz, sw};
    int f0 = chunk << 2;
#pragma unroll
    for (int c = 0; c < 4; c++) {
      int f = f0 + c;
      if (f < Fstore) {
        float v = alpha * vv[c];
        if (add)  v += beta * add[(size_t)node * lda + f];
        if (bias) v += bias[f];
        if (relu) v = fmaxf(v, 0.f);
        Y[(size_t)node * ldy + f] = v;
      }
    }
  }
}

// ---------------- softmax over last dim (F=19) ----------------

__global__ __launch_bounds__(256) void softmax_kernel(float* __restrict__ Y, int n, int F) {
  int i = blockIdx.x * 256 + threadIdx.x;
  if (i >= n) return;
  float* row = Y + (size_t)i * F;
  float m = row[0];
  for (int f = 1; f < F; f++) m = fmaxf(m, row[f]);
  float s = 0.0f;
  for (int f = 0; f < F; f++) s += expf(row[f] - m);
  float inv = 1.0f / s;
  for (int f = 0; f < F; f++) row[f] = expf(row[f] - m) * inv;
}

// ---------------- host orchestration ----------------

static void spmm(hipStream_t s, const int* off, const int* csrc, const float* cw,
                 const float* X, int ldx, float* Y, int ldy,
                 const float* add, int lda, const float* bias,
                 float alpha, float beta, int C_log2, int Fstore, int relu) {
  spmm_kernel<<<(NN + 3) / 4, 256, 0, s>>>(off, csrc, cw, X, ldx, Y, ldy, add, lda,
                                           bias, alpha, beta, NN, C_log2, Fstore, relu);
}

extern "C" void kernel_launch(void* const* d_in, const int* in_sizes, int n_in,
                              void* d_out, int out_size, void* d_ws, size_t ws_size,
                              hipStream_t stream) {
  const float* x  = (const float*)d_in[0];
  const int*   ei = (const int*)d_in[1];
  const float* W1 = (const float*)d_in[2];
  const float* b1 = (const float*)d_in[3];
  const float* W2 = (const float*)d_in[4];
  const float* b2 = (const float*)d_in[5];
  const float* W3 = (const float*)d_in[6];
  const float* b3 = (const float*)d_in[7];
  const float* W4 = (const float*)d_in[8];
  const float* b4 = (const float*)d_in[9];
  const float* W5 = (const float*)d_in[10];
  const float* b5 = (const float*)d_in[11];
  float* out = (float*)d_out;
  const int* src = ei;
  const int* dst = ei + NE;
  (void)in_sizes; (void)n_in; (void)out_size; (void)ws_size;

  char* p = (char*)d_ws;
  auto alloc = [&](size_t bytes) {
    char* r = p;
    p += (bytes + 255) & ~(size_t)255;
    return r;
  };
  int*   i_deg  = (int*)alloc(sizeof(int) * NN * 3);  // deg, cnt, pos (one memset)
  int*   i_cnt  = i_deg + NN;
  int*   i_pos  = i_cnt + NN;
  float* f_dinv = (float*)alloc(sizeof(float) * NN);
  int*   i_off  = (int*)alloc(sizeof(int) * (NN + 1));
  int*   i_csrc = (int*)alloc(sizeof(int) * NE);
  float* f_cw   = (float*)alloc(sizeof(float) * NE);
  float* wc1    = (float*)alloc(sizeof(float) * 782 * 48);
  float* wc5    = (float*)alloc(sizeof(float) * 128 * 60);
  float* R1     = (float*)alloc(sizeof(float) * NN * 96);   // ABC1(48) -> B3(96) -> ABC5(60)
  float* R2     = (float*)alloc(sizeof(float) * NN * 192);  // E1(16) -> B4(192) -> E5(32)
  float* R3     = (float*)alloc(sizeof(float) * NN * 128);  // B2(48) -> H4(128)

  float* ABC1 = R1;
  float* E1   = R2;
  float* B2   = R3;
  float* B3   = R1;
  float* B4   = R2;
  float* H4   = R3;
  float* ABC5 = R1;
  float* E5   = R2;

  // ---- structure ----
  hipMemsetAsync(i_deg, 0, sizeof(int) * NN * 3, stream);
  hipMemsetAsync(ABC1, 0, sizeof(float) * NN * 48, stream);  // split-K atomic target
  deg_kernel<<<(NE + 255) / 256, 256, 0, stream>>>(src, dst, i_deg, i_cnt, NE);
  scan_dinv_kernel<<<1, 1024, 0, stream>>>(i_cnt, i_off, i_deg, f_dinv, NN);
  fill_kernel<<<(NE + 255) / 256, 256, 0, stream>>>(src, dst, f_dinv, i_off, i_pos,
                                                    i_csrc, f_cw, NE);
  wcat_kernel<<<(782 * 48 + 255) / 256, 256, 0, stream>>>(W1, wc1, 782, 16, 16);
  wcat_kernel<<<(128 * 60 + 255) / 256, 256, 0, stream>>>(W5, wc5, 128, 19, 20);

  // ---- Layer 1 (push-through, 782 -> 16): ABC = X @ Wc1, split-K=4 atomic ----
  gemm_rs_kernel<48, false><<<dim3(40, 1, 4), 256, 0, stream>>>(
      x, 782, wc1, 48, nullptr, ABC1, 48, NN, 196, 782, 48, 0, 1);
  // E1 = 2*L(C) + B
  spmm(stream, i_off, i_csrc, f_cw, ABC1 + 32, 48, E1, 16, ABC1 + 16, 48, nullptr,
       2.f, 1.f, 2, 16, 0);
  // H1 = relu(L(E1) + A + b1) -> B2 slot0 (ld 48)
  spmm(stream, i_off, i_csrc, f_cw, E1, 16, B2, 48, ABC1, 48, b1,
       1.f, 1.f, 2, 16, 1);

  // ---- Layer 2 (fused standard, 16 -> 32): concat [T0|T1|T2] in B2 (ld 48) ----
  spmm(stream, i_off, i_csrc, f_cw, B2, 48, B2 + 16, 48, nullptr, 0, nullptr,
       1.f, 0.f, 2, 16, 0);                                           // T1
  spmm(stream, i_off, i_csrc, f_cw, B2 + 16, 48, B2 + 32, 48, B2, 48, nullptr,
       2.f, -1.f, 2, 16, 0);                                          // T2
  gemm_rs_kernel<32, true><<<dim3(40, 1, 1), 256, 0, stream>>>(
      B2, 48, W2, 32, b2, B3, 96, NN, 48, 48, 32, 1, 0);              // H2 -> B3 slot0

  // ---- Layer 3 (32 -> 64), concat in B3 (ld 96) ----
  spmm(stream, i_off, i_csrc, f_cw, B3, 96, B3 + 32, 96, nullptr, 0, nullptr,
       1.f, 0.f, 3, 32, 0);
  spmm(stream, i_off, i_csrc, f_cw, B3 + 32, 96, B3 + 64, 96, B3, 96, nullptr,
       2.f, -1.f, 3, 32, 0);
  gemm_rs_kernel<32, true><<<dim3(40, 2, 1), 256, 0, stream>>>(
      B3, 96, W3, 64, b3, B4, 192, NN, 96, 96, 64, 1, 0);             // H3 -> B4 slot0

  // ---- Layer 4 (64 -> 128), concat in B4 (ld 192) ----
  spmm(stream, i_off, i_csrc, f_cw, B4, 192, B4 + 64, 192, nullptr, 0, nullptr,
       1.f, 0.f, 4, 64, 0);
  spmm(stream, i_off, i_csrc, f_cw, B4 + 64, 192, B4 + 128, 192, B4, 192, nullptr,
       2.f, -1.f, 4, 64, 0);
  gemm_rs_kernel<32, true><<<dim3(40, 4, 1), 256, 0, stream>>>(
      B4, 192, W4, 128, b4, H4, 128, NN, 192, 192, 128, 1, 0);        // H4 (ld 128)

  // ---- Layer 5 (push-through, 128 -> 19 padded 20): ABC = H4 @ Wc5 ----
  gemm_rs_kernel<32, true><<<dim3(40, 2, 1), 256, 0, stream>>>(
      H4, 128, wc5, 60, nullptr, ABC5, 60, NN, 128, 128, 60, 0, 0);
  // E5 = 2*L(C) + B   (C=8 chunks cover 32 cols; cols >= 20 masked at store)
  spmm(stream, i_off, i_csrc, f_cw, ABC5 + 40, 60, E5, 32, ABC5 + 20, 60, nullptr,
       2.f, 1.f, 3, 20, 0);
  // out = L(E5) + A + b5  (ld 19)
  spmm(stream, i_off, i_csrc, f_cw, E5, 32, out, 19, ABC5, 60, b5,
       1.f, 1.f, 3, 19, 0);

  softmax_kernel<<<(NN + 255) / 256, 256, 0, stream>>>(out, NN, 19);
}

// Round 3
// 429.702 us; speedup vs baseline: 1.2657x; 1.2657x over previous
//
#include <hip/hip_runtime.h>
#include <math.h>

#define NN 10000
#define NE 160000

// ---------------- CSR build ----------------

__global__ __launch_bounds__(256) void deg_kernel(const int* __restrict__ src,
                                                  const int* __restrict__ dst,
                                                  int* __restrict__ deg,
                                                  int* __restrict__ cnt, int E) {
  int e = blockIdx.x * 256 + threadIdx.x;
  if (e < E) {
    atomicAdd(&deg[src[e]], 1);
    atomicAdd(&cnt[dst[e]], 1);
  }
}

// fused: dinv (from deg-by-src) + exclusive scan of cnt (by dst) -> off
__global__ __launch_bounds__(1024) void scan_dinv_kernel(const int* __restrict__ cnt,
                                                         int* __restrict__ off,
                                                         const int* __restrict__ deg,
                                                         float* __restrict__ dinv, int n) {
  __shared__ int sh[1024];
  int t = threadIdx.x;
  for (int i = t; i < n; i += 1024) {
    int d = deg[i];
    dinv[i] = d > 0 ? 1.0f / sqrtf((float)d) : 0.0f;
  }
  int per = (n + 1023) / 1024;
  int base = t * per;
  int sum = 0;
  for (int i = 0; i < per; i++) {
    int idx = base + i;
    if (idx < n) sum += cnt[idx];
  }
  sh[t] = sum;
  __syncthreads();
  for (int d = 1; d < 1024; d <<= 1) {
    int v = (t >= d) ? sh[t - d] : 0;
    __syncthreads();
    if (t >= d) sh[t] += v;
    __syncthreads();
  }
  int run = (t > 0) ? sh[t - 1] : 0;
  for (int i = 0; i < per; i++) {
    int idx = base + i;
    if (idx < n) { off[idx] = run; run += cnt[idx]; }
  }
  if (t == 0) off[n] = sh[1023];
}

__global__ __launch_bounds__(256) void fill_kernel(const int* __restrict__ src,
                                                   const int* __restrict__ dst,
                                                   const float* __restrict__ dinv,
                                                   const int* __restrict__ off,
                                                   int* __restrict__ pos,
                                                   int* __restrict__ csrc,
                                                   float* __restrict__ cw, int E) {
  int e = blockIdx.x * 256 + threadIdx.x;
  if (e < E) {
    int s = src[e], d = dst[e];
    int slot = off[d] + atomicAdd(&pos[d], 1);
    csrc[slot] = s;
    cw[slot] = -dinv[s] * dinv[d];
  }
}

// ---------------- weight concat (both push-through layers, one launch) -------
// Wc [Fin][3*Fp]: cols [0,Fp)=W0-W2, [Fp,2Fp)=W1, [2Fp,3Fp)=W2 ; pad cols zero

__device__ __forceinline__ void wcat_one(const float* __restrict__ W,
                                         float* __restrict__ Wc,
                                         int i, int Fin, int F, int Fp) {
  int w3 = 3 * Fp;
  int row = i / w3;
  int c = i - row * w3;
  int sec = c / Fp;
  int f = c - sec * Fp;
  float v = 0.0f;
  if (f < F) {
    if (sec == 0)      v = W[row * F + f] - W[2 * Fin * F + row * F + f];
    else if (sec == 1) v = W[Fin * F + row * F + f];
    else               v = W[2 * Fin * F + row * F + f];
  }
  Wc[i] = v;
}

__global__ __launch_bounds__(256) void wcat2_kernel(const float* __restrict__ W1,
                                                    float* __restrict__ wc1,
                                                    const float* __restrict__ W5,
                                                    float* __restrict__ wc5) {
  int i = blockIdx.x * 256 + threadIdx.x;
  const int t1 = 782 * 48;
  const int t5 = 128 * 60;
  if (i < t1) {
    wcat_one(W1, wc1, i, 782, 16, 16);
  } else if (i < t1 + t5) {
    wcat_one(W5, wc5, i - t1, 128, 19, 20);
  }
}

// ---------------- GEMM: thread-per-row + LDS-staged X + scalar-broadcast W ---
// Block = 256 threads = 256 rows. Per 32-k chunk: coalesced float4/float2
// staging into Xs (stride 33 -> conflict-free compute reads). Compute: per k,
// 1 ds_read_b32 (own row) + TN FMAs with W from uniform s_loads. If
// gridDim.z > 1, Y is a per-split partial buffer (plain stores, no atomics).

template <int TN, bool AL16>
__global__ __launch_bounds__(256) void gemm_lds_kernel(
    const float* __restrict__ X, int ldx,
    const float* __restrict__ W, int ldw,
    const float* __restrict__ bias,
    float* __restrict__ Y, int ldy,
    int M, int Kd, int kchunk, int Nd, int relu) {
  __shared__ float Xs[256 * 33];
  int t = threadIdx.x;
  int row0 = blockIdx.x * 256;
  int col0 = blockIdx.y * TN;
  int k0 = blockIdx.z * kchunk;
  int kend = k0 + kchunk;
  if (kend > Kd) kend = Kd;
  if (gridDim.z > 1) Y += (size_t)blockIdx.z * M * ldy;  // partial buffer

  float acc[TN];
#pragma unroll
  for (int c = 0; c < TN; c++) acc[c] = 0.f;

  int rb = t >> 3;        // 0..31
  int kk = (t & 7) << 2;  // 0,4,..,28

  for (int kc = k0; kc < kend; kc += 32) {
    int klen = kend - kc;
    if (klen > 32) klen = 32;
    // stage 256 rows x klen (coalesced: 8 consecutive threads cover 32 k)
#pragma unroll
    for (int i = 0; i < 8; i++) {
      int row = rb + (i << 5);
      int gr = row0 + row;
      float v0 = 0.f, v1 = 0.f, v2 = 0.f, v3 = 0.f;
      if (gr < M && kk < klen) {
        const float* xp = X + (size_t)gr * ldx + kc + kk;
        if (kk + 4 <= klen) {
          if (AL16) {
            float4 v = *(const float4*)xp;
            v0 = v.x; v1 = v.y; v2 = v.z; v3 = v.w;
          } else {  // rows only 8B-aligned (ldx=782)
            float2 a = *(const float2*)xp;
            float2 b = *(const float2*)(xp + 2);
            v0 = a.x; v1 = a.y; v2 = b.x; v3 = b.y;
          }
        } else {
          v0 = xp[0];
          if (kk + 1 < klen) v1 = xp[1];
          if (kk + 2 < klen) v2 = xp[2];
        }
      }
      float* d = Xs + row * 33 + kk;
      d[0] = v0; d[1] = v1; d[2] = v2; d[3] = v3;
    }
    __syncthreads();
    if (row0 + t < M) {
      for (int k = 0; k < klen; k++) {
        float xv = Xs[t * 33 + k];
        const float* wr = W + (size_t)(kc + k) * ldw + col0;  // uniform -> s_load
#pragma unroll
        for (int c = 0; c < TN; c += 4) {
          float4 wv = *(const float4*)(wr + c);
          acc[c + 0] += xv * wv.x;
          acc[c + 1] += xv * wv.y;
          acc[c + 2] += xv * wv.z;
          acc[c + 3] += xv * wv.w;
        }
      }
    }
    __syncthreads();
  }

  int r = row0 + t;
  if (r < M) {
    float* yrow = Y + (size_t)r * ldy + col0;
#pragma unroll
    for (int c = 0; c < TN; c++) {
      int gc = col0 + c;
      if (gc < Nd) {
        float v = acc[c] + (bias ? bias[gc] : 0.f);
        if (relu) v = fmaxf(v, 0.f);
        yrow[c] = v;
      }
    }
  }
}

// sum k-split partials: Y[i] = sum_j P[j*stride + i]
__global__ __launch_bounds__(256) void reduce_kernel(const float* __restrict__ P,
                                                     float* __restrict__ Y,
                                                     int total, int nsplit, int stride) {
  int i = blockIdx.x * 256 + threadIdx.x;
  if (i >= total) return;
  float s = 0.f;
  for (int j = 0; j < nsplit; j++) s += P[(size_t)j * stride + i];
  Y[i] = s;
}

// ---------------- SpMM: wave-per-node (optionally fused softmax) ------------
// lane = eslot * C + chunk; each lane gathers one edge's float4, butterfly-
// reduce over eslot bits. Y = alpha*(L_hat X) + beta*add (+bias)(+relu).
// do_softmax (requires C_log2==3): row softmax across lanes 0..7.

__global__ __launch_bounds__(256) void spmm_kernel(
    const int* __restrict__ off,
    const int* __restrict__ csrc,
    const float* __restrict__ cw,
    const float* __restrict__ X, int ldx,
    float* __restrict__ Y, int ldy,
    const float* __restrict__ add, int lda,
    const float* __restrict__ bias,
    float alpha, float beta,
    int n, int C_log2, int Fstore, int relu, int do_softmax) {
  int wave_in_blk = threadIdx.x >> 6;
  int lane = threadIdx.x & 63;
  int node = blockIdx.x * 4 + wave_in_blk;
  if (node >= n) return;
  int C = 1 << C_log2;
  int chunk = lane & (C - 1);
  int eslot = lane >> C_log2;
  int Epar = 64 >> C_log2;

  int j0 = off[node], j1 = off[node + 1];
  float sx = 0.f, sy = 0.f, sz = 0.f, sw = 0.f;
  for (int j = j0 + eslot; j < j1; j += Epar) {
    int sn = csrc[j];
    float w = cw[j];
    float4 xv = *(const float4*)(X + (size_t)sn * ldx + (chunk << 2));
    sx += w * xv.x; sy += w * xv.y; sz += w * xv.z; sw += w * xv.w;
  }
  for (int st = C; st < 64; st <<= 1) {
    sx += __shfl_xor(sx, st);
    sy += __shfl_xor(sy, st);
    sz += __shfl_xor(sz, st);
    sw += __shfl_xor(sw, st);
  }
  if (eslot == 0) {
    float vv[4] = {sx, sy, sz, sw};
    int f0 = chunk << 2;
    float v[4];
#pragma unroll
    for (int c = 0; c < 4; c++) {
      int f = f0 + c;
      float u = alpha * vv[c];
      if (add) u += beta * add[(size_t)node * lda + f];
      if (bias && f < Fstore) u += bias[f];
      v[c] = u;
    }
    if (!do_softmax) {
#pragma unroll
      for (int c = 0; c < 4; c++) {
        int f = f0 + c;
        if (f < Fstore) {
          float u = v[c];
          if (relu) u = fmaxf(u, 0.f);
          Y[(size_t)node * ldy + f] = u;
        }
      }
    } else {
      // softmax across the 19 valid cols held by lanes 0..7 (4 each)
      float mx = -INFINITY;
#pragma unroll
      for (int c = 0; c < 4; c++)
        if (f0 + c < Fstore) mx = fmaxf(mx, v[c]);
      mx = fmaxf(mx, __shfl_xor(mx, 1));
      mx = fmaxf(mx, __shfl_xor(mx, 2));
      mx = fmaxf(mx, __shfl_xor(mx, 4));
      float e[4];
      float s = 0.f;
#pragma unroll
      for (int c = 0; c < 4; c++) {
        e[c] = (f0 + c < Fstore) ? __expf(v[c] - mx) : 0.f;
        s += e[c];
      }
      s += __shfl_xor(s, 1);
      s += __shfl_xor(s, 2);
      s += __shfl_xor(s, 4);
      float inv = 1.f / s;
#pragma unroll
      for (int c = 0; c < 4; c++) {
        int f = f0 + c;
        if (f < Fstore) Y[(size_t)node * ldy + f] = e[c] * inv;
      }
    }
  }
}

// ---------------- host orchestration ----------------

static void spmm(hipStream_t s, const int* off, const int* csrc, const float* cw,
                 const float* X, int ldx, float* Y, int ldy,
                 const float* add, int lda, const float* bias,
                 float alpha, float beta, int C_log2, int Fstore, int relu,
                 int do_softmax = 0) {
  spmm_kernel<<<(NN + 3) / 4, 256, 0, s>>>(off, csrc, cw, X, ldx, Y, ldy, add, lda,
                                           bias, alpha, beta, NN, C_log2, Fstore,
                                           relu, do_softmax);
}

extern "C" void kernel_launch(void* const* d_in, const int* in_sizes, int n_in,
                              void* d_out, int out_size, void* d_ws, size_t ws_size,
                              hipStream_t stream) {
  const float* x  = (const float*)d_in[0];
  const int*   ei = (const int*)d_in[1];
  const float* W1 = (const float*)d_in[2];
  const float* b1 = (const float*)d_in[3];
  const float* W2 = (const float*)d_in[4];
  const float* b2 = (const float*)d_in[5];
  const float* W3 = (const float*)d_in[6];
  const float* b3 = (const float*)d_in[7];
  const float* W4 = (const float*)d_in[8];
  const float* b4 = (const float*)d_in[9];
  const float* W5 = (const float*)d_in[10];
  const float* b5 = (const float*)d_in[11];
  float* out = (float*)d_out;
  const int* src = ei;
  const int* dst = ei + NE;
  (void)in_sizes; (void)n_in; (void)out_size; (void)ws_size;

  char* p = (char*)d_ws;
  auto alloc = [&](size_t bytes) {
    char* r = p;
    p += (bytes + 255) & ~(size_t)255;
    return r;
  };
  int*   i_deg  = (int*)alloc(sizeof(int) * NN * 3);  // deg, cnt, pos (one memset)
  int*   i_cnt  = i_deg + NN;
  int*   i_pos  = i_cnt + NN;
  float* f_dinv = (float*)alloc(sizeof(float) * NN);
  int*   i_off  = (int*)alloc(sizeof(int) * (NN + 1));
  int*   i_csrc = (int*)alloc(sizeof(int) * NE);
  float* f_cw   = (float*)alloc(sizeof(float) * NE);
  float* wc1    = (float*)alloc(sizeof(float) * 782 * 48);
  float* wc5    = (float*)alloc(sizeof(float) * 128 * 60);
  float* R1     = (float*)alloc(sizeof(float) * NN * 96);   // ABC1(48)->B3(96)->ABC5(60)
  float* R2     = (float*)alloc(sizeof(float) * NN * 192);  // E1(16)->B4(192)->E5(32)
  float* R3     = (float*)alloc(sizeof(float) * NN * 128);  // B2(48)->H4(128)
  float* P      = (float*)alloc(sizeof(float) * 7 * NN * 48);  // L1 k-split partials

  float* ABC1 = R1;
  float* E1   = R2;
  float* B2   = R3;
  float* B3   = R1;
  float* B4   = R2;
  float* H4   = R3;
  float* ABC5 = R1;
  float* E5   = R2;

  // ---- structure ----
  hipMemsetAsync(i_deg, 0, sizeof(int) * NN * 3, stream);
  deg_kernel<<<(NE + 255) / 256, 256, 0, stream>>>(src, dst, i_deg, i_cnt, NE);
  scan_dinv_kernel<<<1, 1024, 0, stream>>>(i_cnt, i_off, i_deg, f_dinv, NN);
  fill_kernel<<<(NE + 255) / 256, 256, 0, stream>>>(src, dst, f_dinv, i_off, i_pos,
                                                    i_csrc, f_cw, NE);
  wcat2_kernel<<<(782 * 48 + 128 * 60 + 255) / 256, 256, 0, stream>>>(W1, wc1, W5, wc5);

  // ---- Layer 1 (push-through, 782 -> 16): ABC = X @ Wc1, k-split 7 x 128 ----
  gemm_lds_kernel<48, false><<<dim3(40, 1, 7), 256, 0, stream>>>(
      x, 782, wc1, 48, nullptr, P, 48, NN, 782, 128, 48, 0);
  reduce_kernel<<<(NN * 48 + 255) / 256, 256, 0, stream>>>(P, ABC1, NN * 48, 7, NN * 48);
  // E1 = 2*L(C) + B
  spmm(stream, i_off, i_csrc, f_cw, ABC1 + 32, 48, E1, 16, ABC1 + 16, 48, nullptr,
       2.f, 1.f, 2, 16, 0);
  // H1 = relu(L(E1) + A + b1) -> B2 slot0 (ld 48)
  spmm(stream, i_off, i_csrc, f_cw, E1, 16, B2, 48, ABC1, 48, b1,
       1.f, 1.f, 2, 16, 1);

  // ---- Layer 2 (fused standard, 16 -> 32): concat [T0|T1|T2] in B2 (ld 48) ----
  spmm(stream, i_off, i_csrc, f_cw, B2, 48, B2 + 16, 48, nullptr, 0, nullptr,
       1.f, 0.f, 2, 16, 0);                                           // T1
  spmm(stream, i_off, i_csrc, f_cw, B2 + 16, 48, B2 + 32, 48, B2, 48, nullptr,
       2.f, -1.f, 2, 16, 0);                                          // T2
  gemm_lds_kernel<32, true><<<dim3(40, 1, 1), 256, 0, stream>>>(
      B2, 48, W2, 32, b2, B3, 96, NN, 48, 48, 32, 1);                 // H2 -> B3 slot0

  // ---- Layer 3 (32 -> 64), concat in B3 (ld 96) ----
  spmm(stream, i_off, i_csrc, f_cw, B3, 96, B3 + 32, 96, nullptr, 0, nullptr,
       1.f, 0.f, 3, 32, 0);
  spmm(stream, i_off, i_csrc, f_cw, B3 + 32, 96, B3 + 64, 96, B3, 96, nullptr,
       2.f, -1.f, 3, 32, 0);
  gemm_lds_kernel<32, true><<<dim3(40, 2, 1), 256, 0, stream>>>(
      B3, 96, W3, 64, b3, B4, 192, NN, 96, 96, 64, 1);                // H3 -> B4 slot0

  // ---- Layer 4 (64 -> 128), concat in B4 (ld 192) ----
  spmm(stream, i_off, i_csrc, f_cw, B4, 192, B4 + 64, 192, nullptr, 0, nullptr,
       1.f, 0.f, 4, 64, 0);
  spmm(stream, i_off, i_csrc, f_cw, B4 + 64, 192, B4 + 128, 192, B4, 192, nullptr,
       2.f, -1.f, 4, 64, 0);
  gemm_lds_kernel<32, true><<<dim3(40, 4, 1), 256, 0, stream>>>(
      B4, 192, W4, 128, b4, H4, 128, NN, 192, 192, 128, 1);           // H4 (ld 128)

  // ---- Layer 5 (push-through, 128 -> 19 padded 20): ABC = H4 @ Wc5 ----
  gemm_lds_kernel<20, true><<<dim3(40, 3, 1), 256, 0, stream>>>(
      H4, 128, wc5, 60, nullptr, ABC5, 60, NN, 128, 128, 60, 0);
  // E5 = 2*L(C) + B   (C=8 chunks cover 32 cols; cols >= 20 masked at store)
  spmm(stream, i_off, i_csrc, f_cw, ABC5 + 40, 60, E5, 32, ABC5 + 20, 60, nullptr,
       2.f, 1.f, 3, 20, 0);
  // out = softmax(L(E5) + A + b5)  (ld 19, fused)
  spmm(stream, i_off, i_csrc, f_cw, E5, 32, out, 19, ABC5, 60, b5,
       1.f, 1.f, 3, 19, 0, 1);
}

// Round 4
// 410.902 us; speedup vs baseline: 1.3236x; 1.0458x over previous
//
#include <hip/hip_runtime.h>
#include <math.h>

#define NN 10000
#define NE 160000

// ---------------- CSR build ----------------

__global__ __launch_bounds__(256) void deg_kernel(const int* __restrict__ src,
                                                  const int* __restrict__ dst,
                                                  int* __restrict__ deg,
                                                  int* __restrict__ cnt, int E) {
  int e = blockIdx.x * 256 + threadIdx.x;
  if (e < E) {
    atomicAdd(&deg[src[e]], 1);
    atomicAdd(&cnt[dst[e]], 1);
  }
}

// fused: dinv (from deg-by-src) + exclusive scan of cnt (by dst) -> off
__global__ __launch_bounds__(1024) void scan_dinv_kernel(const int* __restrict__ cnt,
                                                         int* __restrict__ off,
                                                         const int* __restrict__ deg,
                                                         float* __restrict__ dinv, int n) {
  __shared__ int sh[1024];
  int t = threadIdx.x;
  for (int i = t; i < n; i += 1024) {
    int d = deg[i];
    dinv[i] = d > 0 ? 1.0f / sqrtf((float)d) : 0.0f;
  }
  int per = (n + 1023) / 1024;
  int base = t * per;
  int sum = 0;
  for (int i = 0; i < per; i++) {
    int idx = base + i;
    if (idx < n) sum += cnt[idx];
  }
  sh[t] = sum;
  __syncthreads();
  for (int d = 1; d < 1024; d <<= 1) {
    int v = (t >= d) ? sh[t - d] : 0;
    __syncthreads();
    if (t >= d) sh[t] += v;
    __syncthreads();
  }
  int run = (t > 0) ? sh[t - 1] : 0;
  for (int i = 0; i < per; i++) {
    int idx = base + i;
    if (idx < n) { off[idx] = run; run += cnt[idx]; }
  }
  if (t == 0) off[n] = sh[1023];
}

__global__ __launch_bounds__(256) void fill_kernel(const int* __restrict__ src,
                                                   const int* __restrict__ dst,
                                                   const float* __restrict__ dinv,
                                                   const int* __restrict__ off,
                                                   int* __restrict__ pos,
                                                   int* __restrict__ csrc,
                                                   float* __restrict__ cw, int E) {
  int e = blockIdx.x * 256 + threadIdx.x;
  if (e < E) {
    int s = src[e], d = dst[e];
    int slot = off[d] + atomicAdd(&pos[d], 1);
    csrc[slot] = s;
    cw[slot] = -dinv[s] * dinv[d];
  }
}

// ---------------- weight concat (both push-through layers, one launch) -------
// Wc [Fin][3*Fp]: cols [0,Fp)=W0-W2, [Fp,2Fp)=W1, [2Fp,3Fp)=W2 ; pad cols zero

__device__ __forceinline__ void wcat_one(const float* __restrict__ W,
                                         float* __restrict__ Wc,
                                         int i, int Fin, int F, int Fp) {
  int w3 = 3 * Fp;
  int row = i / w3;
  int c = i - row * w3;
  int sec = c / Fp;
  int f = c - sec * Fp;
  float v = 0.0f;
  if (f < F) {
    if (sec == 0)      v = W[row * F + f] - W[2 * Fin * F + row * F + f];
    else if (sec == 1) v = W[Fin * F + row * F + f];
    else               v = W[2 * Fin * F + row * F + f];
  }
  Wc[i] = v;
}

__global__ __launch_bounds__(256) void wcat2_kernel(const float* __restrict__ W1,
                                                    float* __restrict__ wc1,
                                                    const float* __restrict__ W5,
                                                    float* __restrict__ wc5) {
  int i = blockIdx.x * 256 + threadIdx.x;
  const int t1 = 782 * 48;
  const int t5 = 128 * 60;
  if (i < t1) {
    wcat_one(W1, wc1, i, 782, 16, 16);
  } else if (i < t1 + t5) {
    wcat_one(W5, wc5, i - t1, 128, 19, 20);
  }
}

// ---------------- GEMM v4: 512 rows/block, X and W both in LDS -------------
// Per 16-k chunk: stage X (512x16, stride 17 -> compute reads 2 lanes/bank =
// free) and W (16xTN, read via wave-uniform ds_read_b128 -> broadcast). Inner
// loop fully unrolled (compile-time 16) -> pure ds_read + v_fma, fine-grained
// lgkmcnt (no SMEM mixing). Thread t computes rows row0+t and row0+t+256.
// gridDim.z > 1 -> Y treated as partial buffer P[z][M*ldy] (plain stores).

template <int TN, bool AL16>
__global__ __launch_bounds__(256) void gemm_v4_kernel(
    const float* __restrict__ X, int ldx,
    const float* __restrict__ W, int ldw,
    const float* __restrict__ bias,
    float* __restrict__ Y, int ldy,
    int M, int kchunk, int Kd, int Nd, int relu) {
  __shared__ float Xs[512 * 17];
  __shared__ float Ws[16 * TN];
  constexpr int W4 = TN / 4;
  int t = threadIdx.x;
  int row0 = blockIdx.x * 512;
  int col0 = blockIdx.y * TN;
  int k0 = blockIdx.z * kchunk;
  int kend = k0 + kchunk;
  if (kend > Kd) kend = Kd;
  if (gridDim.z > 1) Y += (size_t)blockIdx.z * M * ldy;

  float acc0[TN], acc1[TN];
#pragma unroll
  for (int c = 0; c < TN; c++) { acc0[c] = 0.f; acc1[c] = 0.f; }

  int kq4 = (t & 3) << 2;  // 0,4,8,12
  int rbase = t >> 2;      // 0..63

  for (int kc = k0; kc < kend; kc += 16) {
    bool fullk = (kc + 16 <= kend);
    // ---- stage W tile: 16 x TN ----
    if (t < 16 * W4) {
      int wk = t / W4;
      int wc = (t - wk * W4) * 4;
      float4 wv = make_float4(0.f, 0.f, 0.f, 0.f);
      if (kc + wk < kend)
        wv = *(const float4*)(W + (size_t)(kc + wk) * ldw + col0 + wc);
      *(float4*)(Ws + wk * TN + wc) = wv;
    }
    // ---- stage X tile: 512 rows x 16 k ----
#pragma unroll
    for (int i = 0; i < 8; i++) {
      int row = rbase + (i << 6);
      int gr = row0 + row;
      float v0 = 0.f, v1 = 0.f, v2 = 0.f, v3 = 0.f;
      if (gr < M) {
        const float* xp = X + (size_t)gr * ldx + kc + kq4;
        if (fullk) {
          if (AL16) {
            float4 v = *(const float4*)xp;
            v0 = v.x; v1 = v.y; v2 = v.z; v3 = v.w;
          } else {
            float2 a = *(const float2*)xp;
            float2 b = *(const float2*)(xp + 2);
            v0 = a.x; v1 = a.y; v2 = b.x; v3 = b.y;
          }
        } else {
          int rem = kend - kc;  // 1..15
          if (kq4 + 0 < rem) v0 = xp[0];
          if (kq4 + 1 < rem) v1 = xp[1];
          if (kq4 + 2 < rem) v2 = xp[2];
          if (kq4 + 3 < rem) v3 = xp[3];
        }
      }
      float* d = Xs + row * 17 + kq4;
      d[0] = v0; d[1] = v1; d[2] = v2; d[3] = v3;
    }
    __syncthreads();
    // ---- compute: 16 k fully unrolled ----
#pragma unroll
    for (int k = 0; k < 16; k++) {
      float x0 = Xs[t * 17 + k];
      float x1 = Xs[(t + 256) * 17 + k];
      const float* wr = Ws + k * TN;
#pragma unroll
      for (int c = 0; c < TN; c += 4) {
        float4 wv = *(const float4*)(wr + c);  // wave-uniform -> LDS broadcast
        acc0[c + 0] += x0 * wv.x; acc0[c + 1] += x0 * wv.y;
        acc0[c + 2] += x0 * wv.z; acc0[c + 3] += x0 * wv.w;
        acc1[c + 0] += x1 * wv.x; acc1[c + 1] += x1 * wv.y;
        acc1[c + 2] += x1 * wv.z; acc1[c + 3] += x1 * wv.w;
      }
    }
    __syncthreads();
  }

  // ---- epilogue ----
#pragma unroll
  for (int h = 0; h < 2; h++) {
    int r = row0 + t + (h << 8);
    if (r < M) {
      float* yr = Y + (size_t)r * ldy + col0;
      float* a = h ? acc1 : acc0;
#pragma unroll
      for (int c = 0; c < TN; c++) {
        float v = a[c] + (bias ? bias[col0 + c] : 0.f);
        if (relu) v = fmaxf(v, 0.f);
        yr[c] = v;
      }
    }
  }
}

// fused k-split reduce + bias + relu: Y[r*ldy+c] = act(sum_j P[j][r*Nd+c] + bias[c])
__global__ __launch_bounds__(256) void reduce_bias_kernel(
    const float* __restrict__ P, float* __restrict__ Y,
    const float* __restrict__ bias,
    int M, int Nd, int ldy, int nsplit, int relu) {
  int i = blockIdx.x * 256 + threadIdx.x;
  int total = M * Nd;
  if (i >= total) return;
  float s = 0.f;
  for (int j = 0; j < nsplit; j++) s += P[(size_t)j * total + i];
  int r = i / Nd, c = i - r * Nd;
  if (bias) s += bias[c];
  if (relu) s = fmaxf(s, 0.f);
  Y[(size_t)r * ldy + c] = s;
}

// ---------------- SpMM: wave-per-node (optionally fused softmax) ------------

__global__ __launch_bounds__(256) void spmm_kernel(
    const int* __restrict__ off,
    const int* __restrict__ csrc,
    const float* __restrict__ cw,
    const float* __restrict__ X, int ldx,
    float* __restrict__ Y, int ldy,
    const float* __restrict__ add, int lda,
    const float* __restrict__ bias,
    float alpha, float beta,
    int n, int C_log2, int Fstore, int relu, int do_softmax) {
  int wave_in_blk = threadIdx.x >> 6;
  int lane = threadIdx.x & 63;
  int node = blockIdx.x * 4 + wave_in_blk;
  if (node >= n) return;
  int C = 1 << C_log2;
  int chunk = lane & (C - 1);
  int eslot = lane >> C_log2;
  int Epar = 64 >> C_log2;

  int j0 = off[node], j1 = off[node + 1];
  float sx = 0.f, sy = 0.f, sz = 0.f, sw = 0.f;
  for (int j = j0 + eslot; j < j1; j += Epar) {
    int sn = csrc[j];
    float w = cw[j];
    float4 xv = *(const float4*)(X + (size_t)sn * ldx + (chunk << 2));
    sx += w * xv.x; sy += w * xv.y; sz += w * xv.z; sw += w * xv.w;
  }
  for (int st = C; st < 64; st <<= 1) {
    sx += __shfl_xor(sx, st);
    sy += __shfl_xor(sy, st);
    sz += __shfl_xor(sz, st);
    sw += __shfl_xor(sw, st);
  }
  if (eslot == 0) {
    float vv[4] = {sx, sy, sz, sw};
    int f0 = chunk << 2;
    float v[4];
#pragma unroll
    for (int c = 0; c < 4; c++) {
      int f = f0 + c;
      float u = alpha * vv[c];
      if (add) u += beta * add[(size_t)node * lda + f];
      if (bias && f < Fstore) u += bias[f];
      v[c] = u;
    }
    if (!do_softmax) {
#pragma unroll
      for (int c = 0; c < 4; c++) {
        int f = f0 + c;
        if (f < Fstore) {
          float u = v[c];
          if (relu) u = fmaxf(u, 0.f);
          Y[(size_t)node * ldy + f] = u;
        }
      }
    } else {
      float mx = -INFINITY;
#pragma unroll
      for (int c = 0; c < 4; c++)
        if (f0 + c < Fstore) mx = fmaxf(mx, v[c]);
      mx = fmaxf(mx, __shfl_xor(mx, 1));
      mx = fmaxf(mx, __shfl_xor(mx, 2));
      mx = fmaxf(mx, __shfl_xor(mx, 4));
      float e[4];
      float s = 0.f;
#pragma unroll
      for (int c = 0; c < 4; c++) {
        e[c] = (f0 + c < Fstore) ? __expf(v[c] - mx) : 0.f;
        s += e[c];
      }
      s += __shfl_xor(s, 1);
      s += __shfl_xor(s, 2);
      s += __shfl_xor(s, 4);
      float inv = 1.f / s;
#pragma unroll
      for (int c = 0; c < 4; c++) {
        int f = f0 + c;
        if (f < Fstore) Y[(size_t)node * ldy + f] = e[c] * inv;
      }
    }
  }
}

// ---------------- host orchestration ----------------

static void spmm(hipStream_t s, const int* off, const int* csrc, const float* cw,
                 const float* X, int ldx, float* Y, int ldy,
                 const float* add, int lda, const float* bias,
                 float alpha, float beta, int C_log2, int Fstore, int relu,
                 int do_softmax = 0) {
  spmm_kernel<<<(NN + 3) / 4, 256, 0, s>>>(off, csrc, cw, X, ldx, Y, ldy, add, lda,
                                           bias, alpha, beta, NN, C_log2, Fstore,
                                           relu, do_softmax);
}

extern "C" void kernel_launch(void* const* d_in, const int* in_sizes, int n_in,
                              void* d_out, int out_size, void* d_ws, size_t ws_size,
                              hipStream_t stream) {
  const float* x  = (const float*)d_in[0];
  const int*   ei = (const int*)d_in[1];
  const float* W1 = (const float*)d_in[2];
  const float* b1 = (const float*)d_in[3];
  const float* W2 = (const float*)d_in[4];
  const float* b2 = (const float*)d_in[5];
  const float* W3 = (const float*)d_in[6];
  const float* b3 = (const float*)d_in[7];
  const float* W4 = (const float*)d_in[8];
  const float* b4 = (const float*)d_in[9];
  const float* W5 = (const float*)d_in[10];
  const float* b5 = (const float*)d_in[11];
  float* out = (float*)d_out;
  const int* src = ei;
  const int* dst = ei + NE;
  (void)in_sizes; (void)n_in; (void)out_size; (void)ws_size;

  char* p = (char*)d_ws;
  auto alloc = [&](size_t bytes) {
    char* r = p;
    p += (bytes + 255) & ~(size_t)255;
    return r;
  };
  int*   i_deg  = (int*)alloc(sizeof(int) * NN * 3);  // deg, cnt, pos (one memset)
  int*   i_cnt  = i_deg + NN;
  int*   i_pos  = i_cnt + NN;
  float* f_dinv = (float*)alloc(sizeof(float) * NN);
  int*   i_off  = (int*)alloc(sizeof(int) * (NN + 1));
  int*   i_csrc = (int*)alloc(sizeof(int) * NE);
  float* f_cw   = (float*)alloc(sizeof(float) * NE);
  float* wc1    = (float*)alloc(sizeof(float) * 782 * 48);
  float* wc5    = (float*)alloc(sizeof(float) * 128 * 60);
  float* R1     = (float*)alloc(sizeof(float) * NN * 96);   // ABC1(48)->B3(96)->ABC5(60)
  float* R2     = (float*)alloc(sizeof(float) * NN * 192);  // E1(16)->B4(192)->E5(32)
  float* R3     = (float*)alloc(sizeof(float) * NN * 128);  // B2(48)->H4(128)
  float* P      = (float*)alloc(sizeof(float) * 3 * NN * 128);  // k-split partials (max)

  float* ABC1 = R1;
  float* E1   = R2;
  float* B2   = R3;
  float* B3   = R1;
  float* B4   = R2;
  float* H4   = R3;
  float* ABC5 = R1;
  float* E5   = R2;

  // ---- structure ----
  hipMemsetAsync(i_deg, 0, sizeof(int) * NN * 3, stream);
  deg_kernel<<<(NE + 255) / 256, 256, 0, stream>>>(src, dst, i_deg, i_cnt, NE);
  scan_dinv_kernel<<<1, 1024, 0, stream>>>(i_cnt, i_off, i_deg, f_dinv, NN);
  fill_kernel<<<(NE + 255) / 256, 256, 0, stream>>>(src, dst, f_dinv, i_off, i_pos,
                                                    i_csrc, f_cw, NE);
  wcat2_kernel<<<(782 * 48 + 128 * 60 + 255) / 256, 256, 0, stream>>>(W1, wc1, W5, wc5);

  // ---- Layer 1 (push-through, 782 -> 16): ABC = X @ Wc1 ----
  gemm_v4_kernel<24, false><<<dim3(20, 2, 7), 256, 0, stream>>>(
      x, 782, wc1, 48, nullptr, P, 48, NN, 128, 782, 48, 0);
  reduce_bias_kernel<<<(NN * 48 + 255) / 256, 256, 0, stream>>>(
      P, ABC1, nullptr, NN, 48, 48, 7, 0);
  // E1 = 2*L(C) + B
  spmm(stream, i_off, i_csrc, f_cw, ABC1 + 32, 48, E1, 16, ABC1 + 16, 48, nullptr,
       2.f, 1.f, 2, 16, 0);
  // H1 = relu(L(E1) + A + b1) -> B2 slot0 (ld 48)
  spmm(stream, i_off, i_csrc, f_cw, E1, 16, B2, 48, ABC1, 48, b1,
       1.f, 1.f, 2, 16, 1);

  // ---- Layer 2 (fused standard, 16 -> 32): concat [T0|T1|T2] in B2 (ld 48) ----
  spmm(stream, i_off, i_csrc, f_cw, B2, 48, B2 + 16, 48, nullptr, 0, nullptr,
       1.f, 0.f, 2, 16, 0);                                           // T1
  spmm(stream, i_off, i_csrc, f_cw, B2 + 16, 48, B2 + 32, 48, B2, 48, nullptr,
       2.f, -1.f, 2, 16, 0);                                          // T2
  gemm_v4_kernel<32, true><<<dim3(20, 1, 3), 256, 0, stream>>>(
      B2, 48, W2, 32, nullptr, P, 32, NN, 16, 48, 32, 0);
  reduce_bias_kernel<<<(NN * 32 + 255) / 256, 256, 0, stream>>>(
      P, B3, b2, NN, 32, 96, 3, 1);                                   // H2 -> B3 slot0

  // ---- Layer 3 (32 -> 64), concat in B3 (ld 96) ----
  spmm(stream, i_off, i_csrc, f_cw, B3, 96, B3 + 32, 96, nullptr, 0, nullptr,
       1.f, 0.f, 3, 32, 0);
  spmm(stream, i_off, i_csrc, f_cw, B3 + 32, 96, B3 + 64, 96, B3, 96, nullptr,
       2.f, -1.f, 3, 32, 0);
  gemm_v4_kernel<32, true><<<dim3(20, 2, 2), 256, 0, stream>>>(
      B3, 96, W3, 64, nullptr, P, 64, NN, 48, 96, 64, 0);
  reduce_bias_kernel<<<(NN * 64 + 255) / 256, 256, 0, stream>>>(
      P, B4, b3, NN, 64, 192, 2, 1);                                  // H3 -> B4 slot0

  // ---- Layer 4 (64 -> 128), concat in B4 (ld 192) ----
  spmm(stream, i_off, i_csrc, f_cw, B4, 192, B4 + 64, 192, nullptr, 0, nullptr,
       1.f, 0.f, 4, 64, 0);
  spmm(stream, i_off, i_csrc, f_cw, B4 + 64, 192, B4 + 128, 192, B4, 192, nullptr,
       2.f, -1.f, 4, 64, 0);
  gemm_v4_kernel<32, true><<<dim3(20, 4, 3), 256, 0, stream>>>(
      B4, 192, W4, 128, nullptr, P, 128, NN, 64, 192, 128, 0);
  reduce_bias_kernel<<<(NN * 128 + 255) / 256, 256, 0, stream>>>(
      P, H4, b4, NN, 128, 128, 3, 1);                                 // H4 (ld 128)

  // ---- Layer 5 (push-through, 128 -> 19 padded 20): ABC = H4 @ Wc5 ----
  gemm_v4_kernel<20, true><<<dim3(20, 3, 2), 256, 0, stream>>>(
      H4, 128, wc5, 60, nullptr, P, 60, NN, 64, 128, 60, 0);
  reduce_bias_kernel<<<(NN * 60 + 255) / 256, 256, 0, stream>>>(
      P, ABC5, nullptr, NN, 60, 60, 2, 0);
  // E5 = 2*L(C) + B   (C=8 chunks cover 32 cols; cols >= 20 masked at store)
  spmm(stream, i_off, i_csrc, f_cw, ABC5 + 40, 60, E5, 32, ABC5 + 20, 60, nullptr,
       2.f, 1.f, 3, 20, 0);
  // out = softmax(L(E5) + A + b5)  (ld 19, fused)
  spmm(stream, i_off, i_csrc, f_cw, E5, 32, out, 19, ABC5, 60, b5,
       1.f, 1.f, 3, 19, 0, 1);
}

// Round 5
// 408.092 us; speedup vs baseline: 1.3327x; 1.0069x over previous
//
#include <hip/hip_runtime.h>
#include <math.h>

#define NN 10000
#define NE 160000

// ---------------- CSR build ----------------

__global__ __launch_bounds__(256) void deg_kernel(const int* __restrict__ src,
                                                  const int* __restrict__ dst,
                                                  int* __restrict__ deg,
                                                  int* __restrict__ cnt, int E) {
  int e = blockIdx.x * 256 + threadIdx.x;
  if (e < E) {
    atomicAdd(&deg[src[e]], 1);
    atomicAdd(&cnt[dst[e]], 1);
  }
}

// fused: dinv (from deg-by-src) + exclusive scan of cnt (by dst) -> off
__global__ __launch_bounds__(1024) void scan_dinv_kernel(const int* __restrict__ cnt,
                                                         int* __restrict__ off,
                                                         const int* __restrict__ deg,
                                                         float* __restrict__ dinv, int n) {
  __shared__ int sh[1024];
  int t = threadIdx.x;
  for (int i = t; i < n; i += 1024) {
    int d = deg[i];
    dinv[i] = d > 0 ? 1.0f / sqrtf((float)d) : 0.0f;
  }
  int per = (n + 1023) / 1024;
  int base = t * per;
  int sum = 0;
  for (int i = 0; i < per; i++) {
    int idx = base + i;
    if (idx < n) sum += cnt[idx];
  }
  sh[t] = sum;
  __syncthreads();
  for (int d = 1; d < 1024; d <<= 1) {
    int v = (t >= d) ? sh[t - d] : 0;
    __syncthreads();
    if (t >= d) sh[t] += v;
    __syncthreads();
  }
  int run = (t > 0) ? sh[t - 1] : 0;
  for (int i = 0; i < per; i++) {
    int idx = base + i;
    if (idx < n) { off[idx] = run; run += cnt[idx]; }
  }
  if (t == 0) off[n] = sh[1023];
}

__global__ __launch_bounds__(256) void fill_kernel(const int* __restrict__ src,
                                                   const int* __restrict__ dst,
                                                   const float* __restrict__ dinv,
                                                   const int* __restrict__ off,
                                                   int* __restrict__ pos,
                                                   int* __restrict__ csrc,
                                                   float* __restrict__ cw, int E) {
  int e = blockIdx.x * 256 + threadIdx.x;
  if (e < E) {
    int s = src[e], d = dst[e];
    int slot = off[d] + atomicAdd(&pos[d], 1);
    csrc[slot] = s;
    cw[slot] = -dinv[s] * dinv[d];
  }
}

// ---------------- weight concat (both push-through layers, one launch) -------
// Wc [Fin][3*Fp]: cols [0,Fp)=W0-W2, [Fp,2Fp)=W1, [2Fp,3Fp)=W2 ; pad cols zero

__device__ __forceinline__ void wcat_one(const float* __restrict__ W,
                                         float* __restrict__ Wc,
                                         int i, int Fin, int F, int Fp) {
  int w3 = 3 * Fp;
  int row = i / w3;
  int c = i - row * w3;
  int sec = c / Fp;
  int f = c - sec * Fp;
  float v = 0.0f;
  if (f < F) {
    if (sec == 0)      v = W[row * F + f] - W[2 * Fin * F + row * F + f];
    else if (sec == 1) v = W[Fin * F + row * F + f];
    else               v = W[2 * Fin * F + row * F + f];
  }
  Wc[i] = v;
}

__global__ __launch_bounds__(256) void wcat2_kernel(const float* __restrict__ W1,
                                                    float* __restrict__ wc1,
                                                    const float* __restrict__ W5,
                                                    float* __restrict__ wc5) {
  int i = blockIdx.x * 256 + threadIdx.x;
  const int t1 = 782 * 48;
  const int t5 = 128 * 60;
  if (i < t1) {
    wcat_one(W1, wc1, i, 782, 16, 16);
  } else if (i < t1 + t5) {
    wcat_one(W5, wc5, i - t1, 128, 19, 20);
  }
}

// ---------------- GEMM v5 ----------------------------------------------------
// 512 rows/block (2 rows/thread), TN cols (= full Nd per y-block). W k-slice
// staged into LDS once per block, read via wave-uniform ds_read_b128
// (broadcast). X staged in 16-k chunks with REGISTER double-buffering: chunk
// i+1's global loads are issued before computing chunk i, so one chunk of
// FMAs (~3-4k cyc) hides HBM latency. Xs stride 20 -> b128 reads/writes are
// 4-bank-aligned partitions = zero conflicts. Always writes k-split partials
// P[z][M*Nd] (plain stores). LDS <= 56 KB -> 2 blocks/CU.

template <int TN, int MAXKC, bool AL16>
__global__ __launch_bounds__(256, 2) void gemm_v5_kernel(
    const float* __restrict__ X, int ldx,
    const float* __restrict__ W, int ldw,
    float* __restrict__ P,
    int M, int Kd, int kchunk, int Nd) {
  __shared__ float Xs[512 * 20];
  __shared__ float Ws[MAXKC * TN];
  int t = threadIdx.x;
  int row0 = blockIdx.x * 512;
  int col0 = blockIdx.y * TN;
  int k0 = blockIdx.z * kchunk;
  int kend = k0 + kchunk;
  if (kend > Kd) kend = Kd;
  P += (size_t)blockIdx.z * M * Nd;

  // ---- stage W slice [k0,kend) x TN (zero-filled to MAXKC) ----
  constexpr int W4 = TN / 4;
  for (int idx = t; idx < MAXKC * W4; idx += 256) {
    int wk = idx / W4;
    int wc = (idx - wk * W4) * 4;
    float4 wv = make_float4(0.f, 0.f, 0.f, 0.f);
    if (k0 + wk < kend)
      wv = *(const float4*)(W + (size_t)(k0 + wk) * ldw + col0 + wc);
    *(float4*)(Ws + wk * TN + wc) = wv;
  }

  float acc0[TN], acc1[TN];
#pragma unroll
  for (int c = 0; c < TN; c++) { acc0[c] = 0.f; acc1[c] = 0.f; }

  int rbase = t >> 2;        // 0..63
  int kq4 = (t & 3) << 2;    // 0,4,8,12
  float4 xr[2][8];
  int nchunks = (kend - k0 + 15) >> 4;

  auto load_chunk = [&](int kc, float4* xr8) {
    bool fullk = (kc + 16 <= kend);
#pragma unroll
    for (int i = 0; i < 8; i++) {
      int gr = row0 + rbase + (i << 6);
      float4 v = make_float4(0.f, 0.f, 0.f, 0.f);
      if (gr < M) {
        const float* xp = X + (size_t)gr * ldx + kc + kq4;
        if (fullk) {
          if (AL16) {
            v = *(const float4*)xp;
          } else {  // rows only 8B-aligned (ldx=782)
            float2 a = *(const float2*)xp;
            float2 b = *(const float2*)(xp + 2);
            v = make_float4(a.x, a.y, b.x, b.y);
          }
        } else {
          int rem = kend - kc;  // 1..15
          if (kq4 + 0 < rem) v.x = xp[0];
          if (kq4 + 1 < rem) v.y = xp[1];
          if (kq4 + 2 < rem) v.z = xp[2];
          if (kq4 + 3 < rem) v.w = xp[3];
        }
      }
      xr8[i] = v;
    }
  };

  load_chunk(k0, xr[0]);
  for (int ci = 0; ci < nchunks; ci++) {
    if (ci + 1 < nchunks) load_chunk(k0 + (ci + 1) * 16, xr[(ci + 1) & 1]);
    __syncthreads();  // previous compute done (Xs free); Ws ready on ci==0
    float4* cur = xr[ci & 1];
#pragma unroll
    for (int i = 0; i < 8; i++)
      *(float4*)(Xs + (rbase + (i << 6)) * 20 + kq4) = cur[i];
    __syncthreads();  // Xs visible
    int kb = ci << 4;
    for (int kg = 0; kg < 4; kg++) {
      float4 xa = *(const float4*)(Xs + t * 20 + (kg << 2));
      float4 xb = *(const float4*)(Xs + (t + 256) * 20 + (kg << 2));
      float xs0[4] = {xa.x, xa.y, xa.z, xa.w};
      float xs1[4] = {xb.x, xb.y, xb.z, xb.w};
#pragma unroll
      for (int j = 0; j < 4; j++) {
        const float* wr = Ws + (kb + (kg << 2) + j) * TN;
#pragma unroll
        for (int c = 0; c < TN; c += 4) {
          float4 wv = *(const float4*)(wr + c);  // wave-uniform -> broadcast
          acc0[c + 0] += xs0[j] * wv.x; acc0[c + 1] += xs0[j] * wv.y;
          acc0[c + 2] += xs0[j] * wv.z; acc0[c + 3] += xs0[j] * wv.w;
          acc1[c + 0] += xs1[j] * wv.x; acc1[c + 1] += xs1[j] * wv.y;
          acc1[c + 2] += xs1[j] * wv.z; acc1[c + 3] += xs1[j] * wv.w;
        }
      }
    }
  }

  // ---- store partials (float4) ----
#pragma unroll
  for (int h = 0; h < 2; h++) {
    int r = row0 + t + (h << 8);
    if (r < M) {
      float* pr = P + (size_t)r * Nd + col0;
      float* a = h ? acc1 : acc0;
#pragma unroll
      for (int c = 0; c < TN; c += 4)
        *(float4*)(pr + c) = make_float4(a[c], a[c + 1], a[c + 2], a[c + 3]);
    }
  }
}

// fused k-split reduce + bias + relu: Y[r*ldy+c] = act(sum_j P[j][r*Nd+c] + bias[c])
__global__ __launch_bounds__(256) void reduce_bias_kernel(
    const float* __restrict__ P, float* __restrict__ Y,
    const float* __restrict__ bias,
    int M, int Nd, int ldy, int nsplit, int relu) {
  int i = blockIdx.x * 256 + threadIdx.x;
  int total = M * Nd;
  if (i >= total) return;
  float s = 0.f;
  for (int j = 0; j < nsplit; j++) s += P[(size_t)j * total + i];
  int r = i / Nd, c = i - r * Nd;
  if (bias) s += bias[c];
  if (relu) s = fmaxf(s, 0.f);
  Y[(size_t)r * ldy + c] = s;
}

// ---------------- SpMM: wave-per-node (optionally fused softmax) ------------

__global__ __launch_bounds__(256) void spmm_kernel(
    const int* __restrict__ off,
    const int* __restrict__ csrc,
    const float* __restrict__ cw,
    const float* __restrict__ X, int ldx,
    float* __restrict__ Y, int ldy,
    const float* __restrict__ add, int lda,
    const float* __restrict__ bias,
    float alpha, float beta,
    int n, int C_log2, int Fstore, int relu, int do_softmax) {
  int wave_in_blk = threadIdx.x >> 6;
  int lane = threadIdx.x & 63;
  int node = blockIdx.x * 4 + wave_in_blk;
  if (node >= n) return;
  int C = 1 << C_log2;
  int chunk = lane & (C - 1);
  int eslot = lane >> C_log2;
  int Epar = 64 >> C_log2;

  int j0 = off[node], j1 = off[node + 1];
  float sx = 0.f, sy = 0.f, sz = 0.f, sw = 0.f;
  for (int j = j0 + eslot; j < j1; j += Epar) {
    int sn = csrc[j];
    float w = cw[j];
    float4 xv = *(const float4*)(X + (size_t)sn * ldx + (chunk << 2));
    sx += w * xv.x; sy += w * xv.y; sz += w * xv.z; sw += w * xv.w;
  }
  for (int st = C; st < 64; st <<= 1) {
    sx += __shfl_xor(sx, st);
    sy += __shfl_xor(sy, st);
    sz += __shfl_xor(sz, st);
    sw += __shfl_xor(sw, st);
  }
  if (eslot == 0) {
    float vv[4] = {sx, sy, sz, sw};
    int f0 = chunk << 2;
    float v[4];
#pragma unroll
    for (int c = 0; c < 4; c++) {
      int f = f0 + c;
      float u = alpha * vv[c];
      if (add) u += beta * add[(size_t)node * lda + f];
      if (bias && f < Fstore) u += bias[f];
      v[c] = u;
    }
    if (!do_softmax) {
#pragma unroll
      for (int c = 0; c < 4; c++) {
        int f = f0 + c;
        if (f < Fstore) {
          float u = v[c];
          if (relu) u = fmaxf(u, 0.f);
          Y[(size_t)node * ldy + f] = u;
        }
      }
    } else {
      float mx = -INFINITY;
#pragma unroll
      for (int c = 0; c < 4; c++)
        if (f0 + c < Fstore) mx = fmaxf(mx, v[c]);
      mx = fmaxf(mx, __shfl_xor(mx, 1));
      mx = fmaxf(mx, __shfl_xor(mx, 2));
      mx = fmaxf(mx, __shfl_xor(mx, 4));
      float e[4];
      float s = 0.f;
#pragma unroll
      for (int c = 0; c < 4; c++) {
        e[c] = (f0 + c < Fstore) ? __expf(v[c] - mx) : 0.f;
        s += e[c];
      }
      s += __shfl_xor(s, 1);
      s += __shfl_xor(s, 2);
      s += __shfl_xor(s, 4);
      float inv = 1.f / s;
#pragma unroll
      for (int c = 0; c < 4; c++) {
        int f = f0 + c;
        if (f < Fstore) Y[(size_t)node * ldy + f] = e[c] * inv;
      }
    }
  }
}

// ---------------- host orchestration ----------------

static void spmm(hipStream_t s, const int* off, const int* csrc, const float* cw,
                 const float* X, int ldx, float* Y, int ldy,
                 const float* add, int lda, const float* bias,
                 float alpha, float beta, int C_log2, int Fstore, int relu,
                 int do_softmax = 0) {
  spmm_kernel<<<(NN + 3) / 4, 256, 0, s>>>(off, csrc, cw, X, ldx, Y, ldy, add, lda,
                                           bias, alpha, beta, NN, C_log2, Fstore,
                                           relu, do_softmax);
}

extern "C" void kernel_launch(void* const* d_in, const int* in_sizes, int n_in,
                              void* d_out, int out_size, void* d_ws, size_t ws_size,
                              hipStream_t stream) {
  const float* x  = (const float*)d_in[0];
  const int*   ei = (const int*)d_in[1];
  const float* W1 = (const float*)d_in[2];
  const float* b1 = (const float*)d_in[3];
  const float* W2 = (const float*)d_in[4];
  const float* b2 = (const float*)d_in[5];
  const float* W3 = (const float*)d_in[6];
  const float* b3 = (const float*)d_in[7];
  const float* W4 = (const float*)d_in[8];
  const float* b4 = (const float*)d_in[9];
  const float* W5 = (const float*)d_in[10];
  const float* b5 = (const float*)d_in[11];
  float* out = (float*)d_out;
  const int* src = ei;
  const int* dst = ei + NE;
  (void)in_sizes; (void)n_in; (void)out_size; (void)ws_size;

  char* p = (char*)d_ws;
  auto alloc = [&](size_t bytes) {
    char* r = p;
    p += (bytes + 255) & ~(size_t)255;
    return r;
  };
  int*   i_deg  = (int*)alloc(sizeof(int) * NN * 3);  // deg, cnt, pos (one memset)
  int*   i_cnt  = i_deg + NN;
  int*   i_pos  = i_cnt + NN;
  float* f_dinv = (float*)alloc(sizeof(float) * NN);
  int*   i_off  = (int*)alloc(sizeof(int) * (NN + 1));
  int*   i_csrc = (int*)alloc(sizeof(int) * NE);
  float* f_cw   = (float*)alloc(sizeof(float) * NE);
  float* wc1    = (float*)alloc(sizeof(float) * 782 * 48);
  float* wc5    = (float*)alloc(sizeof(float) * 128 * 60);
  float* R1     = (float*)alloc(sizeof(float) * NN * 96);   // ABC1(48)->B3(96)->ABC5(60)
  float* R2     = (float*)alloc(sizeof(float) * NN * 192);  // E1(16)->B4(192)->E5(32)
  float* R3     = (float*)alloc(sizeof(float) * NN * 128);  // B2(48)->H4(128)
  float* P      = (float*)alloc(sizeof(float) * NN * 560);  // k-split partials (max 10x48)

  float* ABC1 = R1;
  float* E1   = R2;
  float* B2   = R3;
  float* B3   = R1;
  float* B4   = R2;
  float* H4   = R3;
  float* ABC5 = R1;
  float* E5   = R2;

  // ---- structure ----
  hipMemsetAsync(i_deg, 0, sizeof(int) * NN * 3, stream);
  deg_kernel<<<(NE + 255) / 256, 256, 0, stream>>>(src, dst, i_deg, i_cnt, NE);
  scan_dinv_kernel<<<1, 1024, 0, stream>>>(i_cnt, i_off, i_deg, f_dinv, NN);
  fill_kernel<<<(NE + 255) / 256, 256, 0, stream>>>(src, dst, f_dinv, i_off, i_pos,
                                                    i_csrc, f_cw, NE);
  wcat2_kernel<<<(782 * 48 + 128 * 60 + 255) / 256, 256, 0, stream>>>(W1, wc1, W5, wc5);

  // ---- Layer 1 (push-through, 782 -> 16): ABC = X @ Wc1 ----
  gemm_v5_kernel<48, 80, false><<<dim3(20, 1, 10), 256, 0, stream>>>(
      x, 782, wc1, 48, P, NN, 782, 80, 48);
  reduce_bias_kernel<<<(NN * 48 + 255) / 256, 256, 0, stream>>>(
      P, ABC1, nullptr, NN, 48, 48, 10, 0);
  // E1 = 2*L(C) + B
  spmm(stream, i_off, i_csrc, f_cw, ABC1 + 32, 48, E1, 16, ABC1 + 16, 48, nullptr,
       2.f, 1.f, 2, 16, 0);
  // H1 = relu(L(E1) + A + b1) -> B2 slot0 (ld 48)
  spmm(stream, i_off, i_csrc, f_cw, E1, 16, B2, 48, ABC1, 48, b1,
       1.f, 1.f, 2, 16, 1);

  // ---- Layer 2 (fused standard, 16 -> 32): concat [T0|T1|T2] in B2 (ld 48) ----
  spmm(stream, i_off, i_csrc, f_cw, B2, 48, B2 + 16, 48, nullptr, 0, nullptr,
       1.f, 0.f, 2, 16, 0);                                           // T1
  spmm(stream, i_off, i_csrc, f_cw, B2 + 16, 48, B2 + 32, 48, B2, 48, nullptr,
       2.f, -1.f, 2, 16, 0);                                          // T2
  gemm_v5_kernel<32, 16, true><<<dim3(20, 1, 3), 256, 0, stream>>>(
      B2, 48, W2, 32, P, NN, 48, 16, 32);
  reduce_bias_kernel<<<(NN * 32 + 255) / 256, 256, 0, stream>>>(
      P, B3, b2, NN, 32, 96, 3, 1);                                   // H2 -> B3 slot0

  // ---- Layer 3 (32 -> 64), concat in B3 (ld 96) ----
  spmm(stream, i_off, i_csrc, f_cw, B3, 96, B3 + 32, 96, nullptr, 0, nullptr,
       1.f, 0.f, 3, 32, 0);
  spmm(stream, i_off, i_csrc, f_cw, B3 + 32, 96, B3 + 64, 96, B3, 96, nullptr,
       2.f, -1.f, 3, 32, 0);
  gemm_v5_kernel<64, 32, true><<<dim3(20, 1, 3), 256, 0, stream>>>(
      B3, 96, W3, 64, P, NN, 96, 32, 64);
  reduce_bias_kernel<<<(NN * 64 + 255) / 256, 256, 0, stream>>>(
      P, B4, b3, NN, 64, 192, 3, 1);                                  // H3 -> B4 slot0

  // ---- Layer 4 (64 -> 128), concat in B4 (ld 192) ----
  spmm(stream, i_off, i_csrc, f_cw, B4, 192, B4 + 64, 192, nullptr, 0, nullptr,
       1.f, 0.f, 4, 64, 0);
  spmm(stream, i_off, i_csrc, f_cw, B4 + 64, 192, B4 + 128, 192, B4, 192, nullptr,
       2.f, -1.f, 4, 64, 0);
  gemm_v5_kernel<64, 48, true><<<dim3(20, 2, 4), 256, 0, stream>>>(
      B4, 192, W4, 128, P, NN, 192, 48, 128);
  reduce_bias_kernel<<<(NN * 128 + 255) / 256, 256, 0, stream>>>(
      P, H4, b4, NN, 128, 128, 4, 1);                                 // H4 (ld 128)

  // ---- Layer 5 (push-through, 128 -> 19 padded 20): ABC = H4 @ Wc5 ----
  gemm_v5_kernel<60, 48, true><<<dim3(20, 1, 3), 256, 0, stream>>>(
      H4, 128, wc5, 60, P, NN, 128, 48, 60);
  reduce_bias_kernel<<<(NN * 60 + 255) / 256, 256, 0, stream>>>(
      P, ABC5, nullptr, NN, 60, 60, 3, 0);
  // E5 = 2*L(C) + B   (C=8 chunks cover 32 cols; cols >= 20 masked at store)
  spmm(stream, i_off, i_csrc, f_cw, ABC5 + 40, 60, E5, 32, ABC5 + 20, 60, nullptr,
       2.f, 1.f, 3, 20, 0);
  // out = softmax(L(E5) + A + b5)  (ld 19, fused)
  spmm(stream, i_off, i_csrc, f_cw, E5, 32, out, 19, ABC5, 60, b5,
       1.f, 1.f, 3, 19, 0, 1);
}